// Round 9
// baseline (561.572 us; speedup 1.0000x reference)
//
#include <hip/hip_runtime.h>
#include <hip/hip_cooperative_groups.h>
#include <math.h>

namespace cg = cooperative_groups;

#define NSB   512   // build-kernel grid blocks == edge chunks == scan width
#define BTH   512   // build-kernel block threads
#define BSH   9     // 512 nodes per bucket
#define BKN   512   // nodes per bucket
#define ESMAX 6272  // max edges per chunk (ceil(3.2M/512)=6250)
#define TPB   8     // 16-node tiles per block in linear1

typedef _Float16 h8  __attribute__((ext_vector_type(8)));
typedef _Float16 h2v __attribute__((ext_vector_type(2)));

// ================= cooperative CSR build =================
// P1 hist -> P2 scan(M) -> P3 chunk counting-sort + coalesced bucket write ->
// P4 per-bucket counting sort -> exact CSR (col2, rs) + dis. One launch.

__global__ void k_build(const int* __restrict__ src, const int* __restrict__ dst,
                        int* __restrict__ hist, int* __restrict__ bsum,
                        unsigned* __restrict__ col, int* __restrict__ col2,
                        int* __restrict__ rs, float* __restrict__ dis,
                        int n, int e, int nbuck) {
    cg::grid_group grid = cg::this_grid();
    __shared__ int lc[512], lsc[512], lofE[512], lcur[512], soff[512];
    __shared__ unsigned sorted[ESMAX];
    __shared__ unsigned char sbuck[ESMAX];

    int tid = threadIdx.x;
    int blk = blockIdx.x;
    int es = (e + NSB - 1) / NSB;
    int lo = blk * es, hi = min(lo + es, e);

    // ---- P1: per-(bucket, block) histogram ----
    lc[tid] = 0;
    __syncthreads();
    for (int i = lo + tid; i < hi; i += BTH)
        atomicAdd(&lc[dst[i] >> BSH], 1);
    __syncthreads();
    for (int i = tid; i < nbuck; i += BTH)
        hist[(size_t)i * NSB + blk] = lc[i];
    grid.sync();

    // ---- P2a: block-local exclusive scan of a contiguous segment ----
    const int M = nbuck * NSB;
    const int seg = (M + NSB - 1) / NSB;          // 196 <= 512
    int sbase = blk * seg;
    int v = 0;
    bool inseg = (tid < seg) && (sbase + tid < M);
    if (inseg) v = hist[sbase + tid];
    lsc[tid] = v;
    __syncthreads();
    for (int ofs = 1; ofs < BTH; ofs <<= 1) {
        int t = (tid >= ofs) ? lsc[tid - ofs] : 0;
        __syncthreads();
        lsc[tid] += t;
        __syncthreads();
    }
    int excl = (tid == 0) ? 0 : lsc[tid - 1];
    if (inseg) hist[sbase + tid] = excl;           // block-local exclusive, in place
    if (tid == BTH - 1) bsum[blk] = lsc[BTH - 1];  // block total
    grid.sync();

    // ---- P2b: block 0 exclusive-scans bsum[NSB] ----
    if (blk == 0) {
        int b0 = bsum[tid];                        // NSB == BTH
        lsc[tid] = b0;
        __syncthreads();
        for (int ofs = 1; ofs < BTH; ofs <<= 1) {
            int t = (tid >= ofs) ? lsc[tid - ofs] : 0;
            __syncthreads();
            lsc[tid] += t;
            __syncthreads();
        }
        bsum[tid] = lsc[tid] - b0;
    }
    grid.sync();

    // ---- P2c: add block offsets -> hist[] is now global exclusive offsets ----
    if (inseg) hist[sbase + tid] += bsum[blk];
    grid.sync();

    // ---- P3: LDS counting sort of this chunk by bucket, coalesced col writes ----
    lc[tid] = 0;
    if (tid < nbuck) soff[tid] = hist[(size_t)tid * NSB + blk];
    __syncthreads();
    for (int i = lo + tid; i < hi; i += BTH)
        atomicAdd(&lc[dst[i] >> BSH], 1);
    __syncthreads();
    lsc[tid] = lc[tid];
    __syncthreads();
    for (int ofs = 1; ofs < BTH; ofs <<= 1) {
        int t = (tid >= ofs) ? lsc[tid - ofs] : 0;
        __syncthreads();
        lsc[tid] += t;
        __syncthreads();
    }
    int ex2 = (tid == 0) ? 0 : lsc[tid - 1];
    lofE[tid] = ex2;
    lcur[tid] = ex2;
    __syncthreads();
    for (int i = lo + tid; i < hi; i += BTH) {
        int d = dst[i];
        int b = d >> BSH;
        int p = atomicAdd(&lcur[b], 1);
        sorted[p] = ((unsigned)src[i] << BSH) | (unsigned)(d & (BKN - 1));
        sbuck[p] = (unsigned char)b;
    }
    __syncthreads();
    int cnt_ = hi - lo;
    for (int i = tid; i < cnt_; i += BTH) {
        int b = sbuck[i];
        col[soff[b] + (i - lofE[b])] = sorted[i];
    }
    grid.sync();

    // ---- P4: per-bucket counting sort by dstLocal -> col2, rs, dis ----
    if (blk < nbuck) {
        int blo = hist[(size_t)blk * NSB];
        int bhi = (blk + 1 < nbuck) ? hist[(size_t)(blk + 1) * NSB] : e;
        lc[tid] = 0;
        __syncthreads();
        for (int i = blo + tid; i < bhi; i += BTH)
            atomicAdd(&lc[col[i] & (BKN - 1u)], 1);
        __syncthreads();
        lsc[tid] = lc[tid];
        __syncthreads();
        for (int ofs = 1; ofs < BTH; ofs <<= 1) {
            int t = (tid >= ofs) ? lsc[tid - ofs] : 0;
            __syncthreads();
            lsc[tid] += t;
            __syncthreads();
        }
        int ex3 = (tid == 0) ? 0 : lsc[tid - 1];
        lcur[tid] = blo + ex3;
        int node = (blk << BSH) + tid;
        if (node < n) {
            rs[node] = blo + ex3;
            dis[node] = rsqrtf((float)(lc[tid] + 1));
        }
        if (blk == 0 && tid == 0) rs[n] = e;
        __syncthreads();
        for (int i = blo + tid; i < bhi; i += BTH) {
            unsigned v2 = col[i];
            int pos = atomicAdd(&lcur[v2 & (BKN - 1u)], 1);
            col2[pos] = (int)(v2 >> BSH);
        }
    }
}

// ================= layer-1 linear: hs[n,16] = (x @ W1) * dis, fp16 out =================

__global__ void k_linear1s(const float* __restrict__ x, const float* __restrict__ W,
                           const float* __restrict__ dis, _Float16* __restrict__ hs,
                           int n, int ntiles) {
    __shared__ float sWT[16 * 132];
    __shared__ float sx[16 * 132];
    int tid = threadIdx.x;
    for (int i = tid; i < 2048; i += 256) {
        int k = i >> 4, c = i & 15;
        sWT[c * 132 + k] = W[i];
    }
    int tile0 = blockIdx.x * TPB;
    const float4* xg4 = (const float4*)x;
    for (int tile = tile0; tile < tile0 + TPB && tile < ntiles; tile++) {
        int nodeBase = tile * 16;
        __syncthreads();
        for (int i = tid; i < 512; i += 256) {
            int nl = i >> 5, k4 = i & 31;
            int nd = nodeBase + nl;
            float4 v = make_float4(0.f, 0.f, 0.f, 0.f);
            if (nd < n) v = xg4[(size_t)nd * 32 + k4];
            *((float4*)(sx + nl * 132 + k4 * 4)) = v;
        }
        __syncthreads();
        int nl = tid >> 4, c = tid & 15;
        int node = nodeBase + nl;
        const float4* xr = (const float4*)(sx + nl * 132);
        const float4* wr = (const float4*)(sWT + c * 132);
        float acc = 0.f;
#pragma unroll
        for (int k4 = 0; k4 < 32; k4++) {
            float4 xv = xr[k4];
            float4 wv = wr[k4];
            acc += xv.x * wv.x + xv.y * wv.y + xv.z * wv.z + xv.w * wv.w;
        }
        if (node < n)
            hs[(size_t)node * 16 + c] = (_Float16)(acc * dis[node]);
    }
}

// ================= fused pull + 16x16 linear =================

__global__ void k_pullA(const _Float16* __restrict__ hs, const int* __restrict__ rs,
                        const int* __restrict__ col2, const float* __restrict__ dis,
                        const float* __restrict__ bb, const float* __restrict__ W,
                        _Float16* __restrict__ hsOut, int n) {
    __shared__ float sW[256];
    __shared__ float sb[16];
    if (threadIdx.x < 256) sW[threadIdx.x] = W[threadIdx.x];
    if (threadIdx.x < 16) sb[threadIdx.x] = bb[threadIdx.x];
    __syncthreads();
    int t = blockIdx.x * blockDim.x + threadIdx.x;
    int node = t >> 1, q = t & 1;
    if (node >= n) return;
    const h8* H = (const h8*)hs;
    h8 self = H[(size_t)node * 2 + q];
    float acc[8];
#pragma unroll
    for (int j = 0; j < 8; j++) acc[j] = (float)self[j];
    int b = rs[node], e2 = rs[node + 1];
    int i = b;
    for (; i + 3 < e2; i += 4) {
        int s0 = col2[i], s1 = col2[i + 1], s2 = col2[i + 2], s3 = col2[i + 3];
        h8 v0 = H[(size_t)s0 * 2 + q];
        h8 v1 = H[(size_t)s1 * 2 + q];
        h8 v2 = H[(size_t)s2 * 2 + q];
        h8 v3 = H[(size_t)s3 * 2 + q];
#pragma unroll
        for (int j = 0; j < 8; j++)
            acc[j] += (float)v0[j] + (float)v1[j] + (float)v2[j] + (float)v3[j];
    }
    for (; i < e2; i++) {
        h8 v = H[(size_t)col2[i] * 2 + q];
#pragma unroll
        for (int j = 0; j < 8; j++) acc[j] += (float)v[j];
    }
    float d = dis[node];
    float va[16];
#pragma unroll
    for (int j = 0; j < 8; j++) {
        int k = q * 8 + j;
        float v = acc[j] * d + sb[k];
        v = v > 0.f ? v : 0.f;
        float other = __shfl_xor(v, 1);
        va[j]     = q ? other : v;
        va[8 + j] = q ? v : other;
    }
    h8 o;
#pragma unroll
    for (int j = 0; j < 8; j++) {
        int c = q * 8 + j;
        float s = 0.f;
#pragma unroll
        for (int k = 0; k < 16; k++) s += va[k] * sW[k * 16 + c];
        o[j] = (_Float16)(s * d);
    }
    ((h8*)hsOut)[(size_t)node * 2 + q] = o;
}

// ================= fused pull + 16x2 linear =================

__global__ void k_pullB(const _Float16* __restrict__ hs, const int* __restrict__ rs,
                        const int* __restrict__ col2, const float* __restrict__ dis,
                        const float* __restrict__ bb, const float* __restrict__ W,
                        _Float16* __restrict__ hs2, int n) {
    __shared__ float sW[32];
    __shared__ float sb[16];
    if (threadIdx.x < 32) sW[threadIdx.x] = W[threadIdx.x];
    if (threadIdx.x < 16) sb[threadIdx.x] = bb[threadIdx.x];
    __syncthreads();
    int t = blockIdx.x * blockDim.x + threadIdx.x;
    int node = t >> 1, q = t & 1;
    if (node >= n) return;
    const h8* H = (const h8*)hs;
    h8 self = H[(size_t)node * 2 + q];
    float acc[8];
#pragma unroll
    for (int j = 0; j < 8; j++) acc[j] = (float)self[j];
    int b = rs[node], e2 = rs[node + 1];
    int i = b;
    for (; i + 3 < e2; i += 4) {
        int s0 = col2[i], s1 = col2[i + 1], s2 = col2[i + 2], s3 = col2[i + 3];
        h8 v0 = H[(size_t)s0 * 2 + q];
        h8 v1 = H[(size_t)s1 * 2 + q];
        h8 v2 = H[(size_t)s2 * 2 + q];
        h8 v3 = H[(size_t)s3 * 2 + q];
#pragma unroll
        for (int j = 0; j < 8; j++)
            acc[j] += (float)v0[j] + (float)v1[j] + (float)v2[j] + (float)v3[j];
    }
    for (; i < e2; i++) {
        h8 v = H[(size_t)col2[i] * 2 + q];
#pragma unroll
        for (int j = 0; j < 8; j++) acc[j] += (float)v[j];
    }
    float d = dis[node];
    float p0 = 0.f, p1 = 0.f;
#pragma unroll
    for (int j = 0; j < 8; j++) {
        int k = q * 8 + j;
        float v = acc[j] * d + sb[k];
        v = v > 0.f ? v : 0.f;
        p0 += v * sW[k * 2 + 0];
        p1 += v * sW[k * 2 + 1];
    }
    p0 += __shfl_xor(p0, 1);
    p1 += __shfl_xor(p1, 1);
    if (q == 0) {
        h2v o;
        o[0] = (_Float16)(p0 * d);
        o[1] = (_Float16)(p1 * d);
        ((h2v*)hs2)[node] = o;
    }
}

// ================= final pull + bias + log_softmax =================

__global__ void k_pull2lsm(const _Float16* __restrict__ hs2, const int* __restrict__ rs,
                           const int* __restrict__ col2, const float* __restrict__ dis,
                           const float* __restrict__ b3, float* __restrict__ out, int n) {
    int node = blockIdx.x * blockDim.x + threadIdx.x;
    if (node >= n) return;
    const h2v* H = (const h2v*)hs2;
    h2v self = H[node];
    float a0 = (float)self[0], a1 = (float)self[1];
    int b = rs[node], e2 = rs[node + 1];
    int i = b;
    for (; i + 3 < e2; i += 4) {
        h2v v0 = H[col2[i]];
        h2v v1 = H[col2[i + 1]];
        h2v v2 = H[col2[i + 2]];
        h2v v3 = H[col2[i + 3]];
        a0 += (float)v0[0] + (float)v1[0] + (float)v2[0] + (float)v3[0];
        a1 += (float)v0[1] + (float)v1[1] + (float)v2[1] + (float)v3[1];
    }
    for (; i < e2; i++) {
        h2v v = H[col2[i]];
        a0 += (float)v[0];
        a1 += (float)v[1];
    }
    float d = dis[node];
    float z0 = a0 * d + b3[0];
    float z1 = a1 * d + b3[1];
    float m = fmaxf(z0, z1);
    float l = m + logf(expf(z0 - m) + expf(z1 - m));
    float2 o = {z0 - l, z1 - l};
    ((float2*)out)[node] = o;
}

// ================= launch =================

extern "C" void kernel_launch(void* const* d_in, const int* in_sizes, int n_in,
                              void* d_out, int out_size, void* d_ws, size_t ws_size,
                              hipStream_t stream) {
    const float* x  = (const float*)d_in[0];
    const int*   ei = (const int*)d_in[1];
    const float* W1 = (const float*)d_in[2];
    const float* b1 = (const float*)d_in[3];
    const float* W2 = (const float*)d_in[4];
    const float* b2 = (const float*)d_in[5];
    const float* W3 = (const float*)d_in[6];
    const float* b3 = (const float*)d_in[7];
    float* out = (float*)d_out;

    const int N = in_sizes[0] / 128;
    const int E = in_sizes[1] / 2;
    const int* src = ei;
    const int* dst = ei + E;

    const int NBUCK = (N + BKN - 1) >> BSH;      // 196 for N=100000 (<= 256)
    const int M = NBUCK * NSB;                   // 100352

    char* ws = (char*)d_ws;
    size_t off = 0;
    auto alloc = [&](size_t bytes) {
        void* p = ws + off;
        off += (bytes + 255) & ~(size_t)255;
        return p;
    };
    int*       hist = (int*)alloc((size_t)M * sizeof(int));
    int*       bsum = (int*)alloc(NSB * sizeof(int));
    unsigned*  col  = (unsigned*)alloc((size_t)E * sizeof(unsigned));
    int*       col2 = (int*)alloc((size_t)E * sizeof(int));
    int*       rs   = (int*)alloc((size_t)(N + 1) * sizeof(int));
    float*     dis  = (float*)alloc((size_t)N * sizeof(float));
    _Float16*  hsA  = (_Float16*)alloc((size_t)N * 16 * sizeof(_Float16));
    _Float16*  hsB  = (_Float16*)alloc((size_t)N * 16 * sizeof(_Float16));
    _Float16*  hs2  = (_Float16*)alloc((size_t)N * 2 * sizeof(_Float16));

    const int B = 256;
    auto g = [&](long long work) { return (int)((work + B - 1) / B); };

    // ---- cooperative CSR build: hist + scan + bucket + sort in ONE launch ----
    {
        int n_ = N, e_ = E, nb_ = NBUCK;
        const int* src_ = src; const int* dst_ = dst;
        int* hist_ = hist; int* bsum_ = bsum; unsigned* col_ = col;
        int* col2_ = col2; int* rs_ = rs; float* dis_ = dis;
        void* args[] = { &src_, &dst_, &hist_, &bsum_, &col_, &col2_,
                         &rs_, &dis_, &n_, &e_, &nb_ };
        hipLaunchCooperativeKernel((const void*)k_build, dim3(NSB), dim3(BTH),
                                   args, 0, stream);
    }

    // ---- layer 1 linear ----
    const int NTILES = (N + 15) / 16;
    k_linear1s<<<(NTILES + TPB - 1) / TPB, B, 0, stream>>>(x, W1, dis, hsA, N, NTILES);

    // ---- agg1 + layer2 linear (fused) ----
    k_pullA<<<g((long long)N * 2), B, 0, stream>>>(hsA, rs, col2, dis, b1, W2, hsB, N);

    // ---- agg2 + layer3 linear (fused) ----
    k_pullB<<<g((long long)N * 2), B, 0, stream>>>(hsB, rs, col2, dis, b2, W3, hs2, N);

    // ---- agg3 + bias + log_softmax (fused) ----
    k_pull2lsm<<<g(N), B, 0, stream>>>(hs2, rs, col2, dis, b3, out, N);
}

// Round 11
// 257.107 us; speedup vs baseline: 2.1842x; 2.1842x over previous
//
#include <hip/hip_runtime.h>
#include <math.h>

#define NSB   512   // edge-chunk blocks for hist/bucket passes
#define BSH   8     // 256 nodes per bucket
#define BKN   256   // nodes per bucket
#define ESMAX 6272  // max edges per chunk (ceil(3.2M/512)=6250)
#define TPB   8     // 16-node tiles per block in linear1

typedef _Float16 h8  __attribute__((ext_vector_type(8)));
typedef _Float16 h2v __attribute__((ext_vector_type(2)));

// ================= exclusive scan (n <= 524288) =================

__global__ void k_scan1(const int* __restrict__ in, int* __restrict__ out,
                        int* __restrict__ bsum, int n) {
    __shared__ int sd[256];
    int base = blockIdx.x * 2048 + threadIdx.x * 8;
    int v[8];
    int ts = 0;
#pragma unroll
    for (int j = 0; j < 8; j++) {
        int idx = base + j;
        v[j] = ts;
        ts += (idx < n) ? in[idx] : 0;
    }
    sd[threadIdx.x] = ts;
    __syncthreads();
    for (int ofs = 1; ofs < 256; ofs <<= 1) {
        int t = (threadIdx.x >= (unsigned)ofs) ? sd[threadIdx.x - ofs] : 0;
        __syncthreads();
        sd[threadIdx.x] += t;
        __syncthreads();
    }
    int excl = (threadIdx.x == 0) ? 0 : sd[threadIdx.x - 1];
#pragma unroll
    for (int j = 0; j < 8; j++) {
        int idx = base + j;
        if (idx < n) out[idx] = excl + v[j];
    }
    if (threadIdx.x == 255) bsum[blockIdx.x] = sd[255];
}

__global__ void k_scan2(int* __restrict__ bsum, int nb) {
    __shared__ int sd[256];
    int orig = (threadIdx.x < (unsigned)nb) ? bsum[threadIdx.x] : 0;
    sd[threadIdx.x] = orig;
    __syncthreads();
    for (int ofs = 1; ofs < 256; ofs <<= 1) {
        int t = (threadIdx.x >= (unsigned)ofs) ? sd[threadIdx.x - ofs] : 0;
        __syncthreads();
        sd[threadIdx.x] += t;
        __syncthreads();
    }
    if (threadIdx.x < (unsigned)nb) bsum[threadIdx.x] = sd[threadIdx.x] - orig;
}

__global__ void k_scan3(int* __restrict__ out, const int* __restrict__ bsum, int n) {
    int i = blockIdx.x * blockDim.x + threadIdx.x;
    if (i < n) out[i] += bsum[i >> 11];
}

// ================= bucketing (256-node buckets) =================

__global__ void k_hist(const int* __restrict__ dst, int* __restrict__ hist,
                       int e, int nbuck, int es) {
    __shared__ int h[512];
    for (int i = threadIdx.x; i < 512; i += blockDim.x) h[i] = 0;
    __syncthreads();
    int lo = blockIdx.x * es;
    int hi = min(lo + es, e);
    for (int i = lo + threadIdx.x; i < hi; i += blockDim.x)
        atomicAdd(&h[dst[i] >> BSH], 1);
    __syncthreads();
    for (int i = threadIdx.x; i < nbuck; i += blockDim.x)
        hist[(size_t)i * gridDim.x + blockIdx.x] = h[i];
}

// LDS-local counting sort by bucket, then contiguous run writes -> coalesced col stores.
// Requires nbuck <= 512 and chunk size <= ESMAX. blockDim = 512.
__global__ void k_bucket(const int* __restrict__ src, const int* __restrict__ dst,
                         const int* __restrict__ offs, unsigned* __restrict__ col,
                         int e, int nbuck, int es) {
    __shared__ unsigned sorted[ESMAX];
    __shared__ unsigned char sbuck[ESMAX];   // low 8 bits of bucket id
    __shared__ int lc[512], lsc[512], lofE[512], lcur[512], soff[512];
    int tid = threadIdx.x;
    lc[tid] = 0;
    if (tid < nbuck) soff[tid] = offs[(size_t)tid * gridDim.x + blockIdx.x];
    __syncthreads();
    int lo = blockIdx.x * es;
    int hi = min(lo + es, e);
    // pass 1: local histogram
    for (int i = lo + tid; i < hi; i += 512)
        atomicAdd(&lc[dst[i] >> BSH], 1);
    __syncthreads();
    // local scan over 512 entries
    lsc[tid] = lc[tid];
    __syncthreads();
    for (int ofs = 1; ofs < 512; ofs <<= 1) {
        int t = (tid >= ofs) ? lsc[tid - ofs] : 0;
        __syncthreads();
        lsc[tid] += t;
        __syncthreads();
    }
    int excl = (tid == 0) ? 0 : lsc[tid - 1];
    lofE[tid] = excl;
    lcur[tid] = excl;
    __syncthreads();
    // pass 2: scatter into LDS (sorted by bucket)
    for (int i = lo + tid; i < hi; i += 512) {
        int d = dst[i];
        int b = d >> BSH;
        int p = atomicAdd(&lcur[b], 1);
        sorted[p] = ((unsigned)src[i] << BSH) | (unsigned)(d & (BKN - 1));
        sbuck[p] = (unsigned char)(b & 255);
    }
    __syncthreads();
    // pass 3: linear sweep -> contiguous per-run global writes. Runs are
    // bucket-ascending, so bit8 of the bucket id = (i >= lofE[256]).
    int cnt_ = hi - lo;
    int split = (nbuck > 256) ? lofE[256] : 0x7fffffff;
    for (int i = tid; i < cnt_; i += 512) {
        int b = sbuck[i] | ((i >= split) ? 256 : 0);
        col[soff[b] + (i - lofE[b])] = sorted[i];
    }
}

// per-bucket counting sort by dstLocal -> exact CSR (col2 = src ids, rs = row starts),
// plus degree -> dis. One block (512 threads) per bucket; 256-wide scan.
__global__ void k_sort(const unsigned* __restrict__ col, const int* __restrict__ offs,
                       int* __restrict__ col2, int* __restrict__ rs,
                       float* __restrict__ dis, int n, int e, int nbuck) {
    __shared__ int cnt[BKN];
    __shared__ int sd[BKN];
    __shared__ int cur[BKN];
    int tid = threadIdx.x;
    int b = blockIdx.x;
    int lo = offs[(size_t)b * NSB];
    int hi = (b + 1 < nbuck) ? offs[(size_t)(b + 1) * NSB] : e;
    if (tid < BKN) cnt[tid] = 0;
    __syncthreads();
    for (int i = lo + tid; i < hi; i += 512)
        atomicAdd(&cnt[col[i] & (BKN - 1u)], 1);
    __syncthreads();
    if (tid < BKN) sd[tid] = cnt[tid];
    __syncthreads();
    for (int ofs = 1; ofs < BKN; ofs <<= 1) {
        int t = (tid < BKN && tid >= ofs) ? sd[tid - ofs] : 0;
        __syncthreads();
        if (tid < BKN) sd[tid] += t;
        __syncthreads();
    }
    if (tid < BKN) {
        int excl = (tid == 0) ? 0 : sd[tid - 1];
        cur[tid] = lo + excl;
        int node = (b << BSH) + tid;
        if (node < n) {
            rs[node] = lo + excl;
            dis[node] = rsqrtf((float)(cnt[tid] + 1));
        }
    }
    if (b == 0 && tid == 0) rs[n] = e;
    __syncthreads();
    for (int i = lo + tid; i < hi; i += 512) {
        unsigned v = col[i];
        int pos = atomicAdd(&cur[v & (BKN - 1u)], 1);
        col2[pos] = (int)(v >> BSH);
    }
}

// ================= layer-1 linear: hs[n,16] = (x @ W1) * dis, fp16 out =================

__global__ void k_linear1s(const float* __restrict__ x, const float* __restrict__ W,
                           const float* __restrict__ dis, _Float16* __restrict__ hs,
                           int n, int ntiles) {
    __shared__ float sWT[16 * 132];
    __shared__ float sx[16 * 132];
    int tid = threadIdx.x;
    for (int i = tid; i < 2048; i += 256) {
        int k = i >> 4, c = i & 15;
        sWT[c * 132 + k] = W[i];
    }
    int tile0 = blockIdx.x * TPB;
    const float4* xg4 = (const float4*)x;
    for (int tile = tile0; tile < tile0 + TPB && tile < ntiles; tile++) {
        int nodeBase = tile * 16;
        __syncthreads();
        for (int i = tid; i < 512; i += 256) {
            int nl = i >> 5, k4 = i & 31;
            int nd = nodeBase + nl;
            float4 v = make_float4(0.f, 0.f, 0.f, 0.f);
            if (nd < n) v = xg4[(size_t)nd * 32 + k4];
            *((float4*)(sx + nl * 132 + k4 * 4)) = v;
        }
        __syncthreads();
        int nl = tid >> 4, c = tid & 15;
        int node = nodeBase + nl;
        const float4* xr = (const float4*)(sx + nl * 132);
        const float4* wr = (const float4*)(sWT + c * 132);
        float acc = 0.f;
#pragma unroll
        for (int k4 = 0; k4 < 32; k4++) {
            float4 xv = xr[k4];
            float4 wv = wr[k4];
            acc += xv.x * wv.x + xv.y * wv.y + xv.z * wv.z + xv.w * wv.w;
        }
        if (node < n)
            hs[(size_t)node * 16 + c] = (_Float16)(acc * dis[node]);
    }
}

// ================= fused pull + 16x16 linear (4 threads/node) =================
// lanes per node: sub=0..3, q=sub&1 (row half), half=sub>>1 (edge-range half).
// combine edge halves via shfl_xor(2), row halves via shfl_xor(1).

__global__ void k_pullA(const _Float16* __restrict__ hs, const int* __restrict__ rs,
                        const int* __restrict__ col2, const float* __restrict__ dis,
                        const float* __restrict__ bb, const float* __restrict__ W,
                        _Float16* __restrict__ hsOut, int n) {
    __shared__ float sW[256];
    __shared__ float sb[16];
    if (threadIdx.x < 256) sW[threadIdx.x] = W[threadIdx.x];
    if (threadIdx.x < 16) sb[threadIdx.x] = bb[threadIdx.x];
    __syncthreads();
    int t = blockIdx.x * blockDim.x + threadIdx.x;
    int node = t >> 2, sub = t & 3;
    int q = sub & 1, half = sub >> 1;
    if (node >= n) return;
    const h8* H = (const h8*)hs;
    float acc[8];
    if (half == 0) {
        h8 self = H[(size_t)node * 2 + q];
#pragma unroll
        for (int j = 0; j < 8; j++) acc[j] = (float)self[j];
    } else {
#pragma unroll
        for (int j = 0; j < 8; j++) acc[j] = 0.f;
    }
    int b = rs[node], e2 = rs[node + 1];
    int mid = b + ((e2 - b) >> 1);
    int i  = half ? mid : b;
    int en = half ? e2  : mid;
    for (; i + 3 < en; i += 4) {
        int s0 = col2[i], s1 = col2[i + 1], s2 = col2[i + 2], s3 = col2[i + 3];
        h8 v0 = H[(size_t)s0 * 2 + q];
        h8 v1 = H[(size_t)s1 * 2 + q];
        h8 v2 = H[(size_t)s2 * 2 + q];
        h8 v3 = H[(size_t)s3 * 2 + q];
#pragma unroll
        for (int j = 0; j < 8; j++)
            acc[j] += (float)v0[j] + (float)v1[j] + (float)v2[j] + (float)v3[j];
    }
    for (; i < en; i++) {
        h8 v = H[(size_t)col2[i] * 2 + q];
#pragma unroll
        for (int j = 0; j < 8; j++) acc[j] += (float)v[j];
    }
#pragma unroll
    for (int j = 0; j < 8; j++) acc[j] += __shfl_xor(acc[j], 2);   // edge halves
    float d = dis[node];
    float va[16];
#pragma unroll
    for (int j = 0; j < 8; j++) {
        int k = q * 8 + j;
        float v = acc[j] * d + sb[k];
        v = v > 0.f ? v : 0.f;
        float other = __shfl_xor(v, 1);                            // row halves
        va[j]     = q ? other : v;
        va[8 + j] = q ? v : other;
    }
    if (half == 0) {
        h8 o;
#pragma unroll
        for (int j = 0; j < 8; j++) {
            int c = q * 8 + j;
            float s = 0.f;
#pragma unroll
            for (int k = 0; k < 16; k++) s += va[k] * sW[k * 16 + c];
            o[j] = (_Float16)(s * d);
        }
        ((h8*)hsOut)[(size_t)node * 2 + q] = o;
    }
}

// ================= fused pull + 16x2 linear (4 threads/node) =================

__global__ void k_pullB(const _Float16* __restrict__ hs, const int* __restrict__ rs,
                        const int* __restrict__ col2, const float* __restrict__ dis,
                        const float* __restrict__ bb, const float* __restrict__ W,
                        _Float16* __restrict__ hs2, int n) {
    __shared__ float sW[32];
    __shared__ float sb[16];
    if (threadIdx.x < 32) sW[threadIdx.x] = W[threadIdx.x];
    if (threadIdx.x < 16) sb[threadIdx.x] = bb[threadIdx.x];
    __syncthreads();
    int t = blockIdx.x * blockDim.x + threadIdx.x;
    int node = t >> 2, sub = t & 3;
    int q = sub & 1, half = sub >> 1;
    if (node >= n) return;
    const h8* H = (const h8*)hs;
    float acc[8];
    if (half == 0) {
        h8 self = H[(size_t)node * 2 + q];
#pragma unroll
        for (int j = 0; j < 8; j++) acc[j] = (float)self[j];
    } else {
#pragma unroll
        for (int j = 0; j < 8; j++) acc[j] = 0.f;
    }
    int b = rs[node], e2 = rs[node + 1];
    int mid = b + ((e2 - b) >> 1);
    int i  = half ? mid : b;
    int en = half ? e2  : mid;
    for (; i + 3 < en; i += 4) {
        int s0 = col2[i], s1 = col2[i + 1], s2 = col2[i + 2], s3 = col2[i + 3];
        h8 v0 = H[(size_t)s0 * 2 + q];
        h8 v1 = H[(size_t)s1 * 2 + q];
        h8 v2 = H[(size_t)s2 * 2 + q];
        h8 v3 = H[(size_t)s3 * 2 + q];
#pragma unroll
        for (int j = 0; j < 8; j++)
            acc[j] += (float)v0[j] + (float)v1[j] + (float)v2[j] + (float)v3[j];
    }
    for (; i < en; i++) {
        h8 v = H[(size_t)col2[i] * 2 + q];
#pragma unroll
        for (int j = 0; j < 8; j++) acc[j] += (float)v[j];
    }
#pragma unroll
    for (int j = 0; j < 8; j++) acc[j] += __shfl_xor(acc[j], 2);   // edge halves
    float d = dis[node];
    float p0 = 0.f, p1 = 0.f;
#pragma unroll
    for (int j = 0; j < 8; j++) {
        int k = q * 8 + j;
        float v = acc[j] * d + sb[k];
        v = v > 0.f ? v : 0.f;
        p0 += v * sW[k * 2 + 0];
        p1 += v * sW[k * 2 + 1];
    }
    p0 += __shfl_xor(p0, 1);   // row halves (same channel both lanes)
    p1 += __shfl_xor(p1, 1);
    if (sub == 0) {
        h2v o;
        o[0] = (_Float16)(p0 * d);
        o[1] = (_Float16)(p1 * d);
        ((h2v*)hs2)[node] = o;
    }
}

// ================= final pull + bias + log_softmax (2 threads/node) =================

__global__ void k_pull2lsm(const _Float16* __restrict__ hs2, const int* __restrict__ rs,
                           const int* __restrict__ col2, const float* __restrict__ dis,
                           const float* __restrict__ b3, float* __restrict__ out, int n) {
    int t = blockIdx.x * blockDim.x + threadIdx.x;
    int node = t >> 1, half = t & 1;
    if (node >= n) return;
    const h2v* H = (const h2v*)hs2;
    float a0 = 0.f, a1 = 0.f;
    if (half == 0) {
        h2v self = H[node];
        a0 = (float)self[0]; a1 = (float)self[1];
    }
    int b = rs[node], e2 = rs[node + 1];
    int mid = b + ((e2 - b) >> 1);
    int i  = half ? mid : b;
    int en = half ? e2  : mid;
    for (; i + 3 < en; i += 4) {
        h2v v0 = H[col2[i]];
        h2v v1 = H[col2[i + 1]];
        h2v v2 = H[col2[i + 2]];
        h2v v3 = H[col2[i + 3]];
        a0 += (float)v0[0] + (float)v1[0] + (float)v2[0] + (float)v3[0];
        a1 += (float)v0[1] + (float)v1[1] + (float)v2[1] + (float)v3[1];
    }
    for (; i < en; i++) {
        h2v v = H[col2[i]];
        a0 += (float)v[0];
        a1 += (float)v[1];
    }
    a0 += __shfl_xor(a0, 1);
    a1 += __shfl_xor(a1, 1);
    if (half == 0) {
        float d = dis[node];
        float z0 = a0 * d + b3[0];
        float z1 = a1 * d + b3[1];
        float m = fmaxf(z0, z1);
        float l = m + logf(expf(z0 - m) + expf(z1 - m));
        float2 o = {z0 - l, z1 - l};
        ((float2*)out)[node] = o;
    }
}

// ================= launch =================

extern "C" void kernel_launch(void* const* d_in, const int* in_sizes, int n_in,
                              void* d_out, int out_size, void* d_ws, size_t ws_size,
                              hipStream_t stream) {
    const float* x  = (const float*)d_in[0];
    const int*   ei = (const int*)d_in[1];
    const float* W1 = (const float*)d_in[2];
    const float* b1 = (const float*)d_in[3];
    const float* W2 = (const float*)d_in[4];
    const float* b2 = (const float*)d_in[5];
    const float* W3 = (const float*)d_in[6];
    const float* b3 = (const float*)d_in[7];
    float* out = (float*)d_out;

    const int N = in_sizes[0] / 128;
    const int E = in_sizes[1] / 2;
    const int* src = ei;
    const int* dst = ei + E;

    const int NBUCK = (N + BKN - 1) >> BSH;      // 391 for N=100000 (<= 512)
    const int M = NBUCK * NSB;                   // 200192
    const int ES = (E + NSB - 1) / NSB;          // 6250 (<= ESMAX)

    char* ws = (char*)d_ws;
    size_t off = 0;
    auto alloc = [&](size_t bytes) {
        void* p = ws + off;
        off += (bytes + 255) & ~(size_t)255;
        return p;
    };
    int*       hist = (int*)alloc((size_t)M * sizeof(int));
    int*       offs = (int*)alloc((size_t)M * sizeof(int));
    int*       bsum = (int*)alloc(256 * sizeof(int));
    unsigned*  col  = (unsigned*)alloc((size_t)E * sizeof(unsigned));
    int*       col2 = (int*)alloc((size_t)E * sizeof(int));
    int*       rs   = (int*)alloc((size_t)(N + 1) * sizeof(int));
    float*     dis  = (float*)alloc((size_t)N * sizeof(float));
    _Float16*  hsA  = (_Float16*)alloc((size_t)N * 16 * sizeof(_Float16));
    _Float16*  hsB  = (_Float16*)alloc((size_t)N * 16 * sizeof(_Float16));
    _Float16*  hs2  = (_Float16*)alloc((size_t)N * 2 * sizeof(_Float16));

    const int B = 256;
    auto g = [&](long long work) { return (int)((work + B - 1) / B); };
    const int NBS = (M + 2047) / 2048;           // 98 <= 256

    // ---- CSR build: bucket (256-node granularity) + per-bucket counting sort ----
    k_hist<<<NSB, B, 0, stream>>>(dst, hist, E, NBUCK, ES);
    k_scan1<<<NBS, 256, 0, stream>>>(hist, offs, bsum, M);
    k_scan2<<<1, 256, 0, stream>>>(bsum, NBS);
    k_scan3<<<g(M), B, 0, stream>>>(offs, bsum, M);
    k_bucket<<<NSB, 512, 0, stream>>>(src, dst, offs, col, E, NBUCK, ES);
    k_sort<<<NBUCK, 512, 0, stream>>>(col, offs, col2, rs, dis, N, E, NBUCK);

    // ---- layer 1 linear ----
    const int NTILES = (N + 15) / 16;
    k_linear1s<<<(NTILES + TPB - 1) / TPB, B, 0, stream>>>(x, W1, dis, hsA, N, NTILES);

    // ---- agg1 + layer2 linear (fused, 4 threads/node) ----
    k_pullA<<<g((long long)N * 4), B, 0, stream>>>(hsA, rs, col2, dis, b1, W2, hsB, N);

    // ---- agg2 + layer3 linear (fused, 4 threads/node) ----
    k_pullB<<<g((long long)N * 4), B, 0, stream>>>(hsB, rs, col2, dis, b2, W3, hs2, N);

    // ---- agg3 + bias + log_softmax (fused, 2 threads/node) ----
    k_pull2lsm<<<g((long long)N * 2), B, 0, stream>>>(hs2, rs, col2, dis, b3, out, N);
}